// Round 1
// baseline (198.930 us; speedup 1.0000x reference)
//
#include <hip/hip_runtime.h>

#define B_   128
#define I_   4608
#define O_   10
#define D_   16
#define IPB  18          // i's per block
#define NBLK 256         // pass-kernel grid (4608 = 256*18)
#define WST  164         // k-stride (floats) in LDS W tile (padded from 160)

// ---------------------------------------------------------------------------
// Pass kernel.
// MODE 0: acc[b,o,d] += sum_i x_hat[b,o,i,d]                  (iter-0 sums, c folded later)
// MODE 1: bd[o] = sum_d v[b,o,d]*x_hat ; c = softmax_o(bd) ; acc += c[o]*x_hat
// Thread mapping: tid = pair*4 + dg ; pair = b (0..127), dg picks d = dg*4..dg*4+3.
// Per i: stage W[.,i,.,.] (1280 floats) into LDS as wl[k][o][d] (k-major).
// ---------------------------------------------------------------------------
template<int MODE>
__global__ __launch_bounds__(512, 1)
void pass_kernel(const float* __restrict__ x,     // [128][4608][8]
                 const float* __restrict__ w,     // [10][4608][16][8]
                 const float* __restrict__ v,     // [128][10][16] (MODE 1 only)
                 float* __restrict__ parts)       // [NBLK][128][10][16]
{
    __shared__ float wl[8 * WST];

    const int tid  = threadIdx.x;
    const int pair = tid >> 2;     // b
    const int dg   = tid & 3;      // d quad
    const int i0   = blockIdx.x * IPB;

    float4 acc[O_];
#pragma unroll
    for (int o = 0; o < O_; ++o) acc[o] = make_float4(0.f, 0.f, 0.f, 0.f);

    float4 vv[O_];
    if (MODE == 1) {
#pragma unroll
        for (int o = 0; o < O_; ++o)
            vv[o] = *reinterpret_cast<const float4*>(v + (pair * O_ + o) * D_ + dg * 4);
    }

    for (int ii = 0; ii < IPB; ++ii) {
        const int i = i0 + ii;

        __syncthreads();   // protect wl reads of previous iteration
        if (tid < 320) {
            // stage: global W[o][i][d][k] (128 contiguous floats per o) -> wl[k][o][d]
            const int o = tid >> 5, q = tid & 31;
            const float4 g = *reinterpret_cast<const float4*>(
                w + ((long)(o * I_ + i)) * 128 + q * 4);
            const int d  = q >> 1;
            const int k0 = (q & 1) * 4;
            wl[(k0 + 0) * WST + o * 16 + d] = g.x;
            wl[(k0 + 1) * WST + o * 16 + d] = g.y;
            wl[(k0 + 2) * WST + o * 16 + d] = g.z;
            wl[(k0 + 3) * WST + o * 16 + d] = g.w;
        }
        __syncthreads();

        // x[b][i][0..7]
        const float4 xa = *reinterpret_cast<const float4*>(x + ((long)pair * I_ + i) * 8);
        const float4 xb = *reinterpret_cast<const float4*>(x + ((long)pair * I_ + i) * 8 + 4);
        const float xk[8] = {xa.x, xa.y, xa.z, xa.w, xb.x, xb.y, xb.z, xb.w};

        // x_hat[o][d-quad]
        float4 xh[O_];
#pragma unroll
        for (int o = 0; o < O_; ++o) {
            float4 h = make_float4(0.f, 0.f, 0.f, 0.f);
#pragma unroll
            for (int k = 0; k < 8; ++k) {
                const float4 wv = *reinterpret_cast<const float4*>(&wl[k * WST + o * 16 + dg * 4]);
                h.x = fmaf(wv.x, xk[k], h.x);
                h.y = fmaf(wv.y, xk[k], h.y);
                h.z = fmaf(wv.z, xk[k], h.z);
                h.w = fmaf(wv.w, xk[k], h.w);
            }
            xh[o] = h;
        }

        if (MODE == 0) {
#pragma unroll
            for (int o = 0; o < O_; ++o) {
                acc[o].x += xh[o].x; acc[o].y += xh[o].y;
                acc[o].z += xh[o].z; acc[o].w += xh[o].w;
            }
        } else {
            // agreement logits bd[o] = sum_d v*xh  (reduce over the 4 dg lanes)
            float bd[O_];
#pragma unroll
            for (int o = 0; o < O_; ++o) {
                float t = xh[o].x * vv[o].x + xh[o].y * vv[o].y +
                          xh[o].z * vv[o].z + xh[o].w * vv[o].w;
                t += __shfl_xor(t, 1);
                t += __shfl_xor(t, 2);
                bd[o] = t;
            }
            // softmax over o (redundant in the 4 lanes of a pair)
            float m = bd[0];
#pragma unroll
            for (int o = 1; o < O_; ++o) m = fmaxf(m, bd[o]);
            float e[O_];
            float s = 0.f;
#pragma unroll
            for (int o = 0; o < O_; ++o) { e[o] = __expf(bd[o] - m); s += e[o]; }
            const float inv = 1.f / s;
#pragma unroll
            for (int o = 0; o < O_; ++o) {
                const float c = e[o] * inv;
                acc[o].x = fmaf(c, xh[o].x, acc[o].x);
                acc[o].y = fmaf(c, xh[o].y, acc[o].y);
                acc[o].z = fmaf(c, xh[o].z, acc[o].z);
                acc[o].w = fmaf(c, xh[o].w, acc[o].w);
            }
        }
    }

    // block-partial write: parts[blk][b][o][d]
    float* p = parts + (long)blockIdx.x * (B_ * O_ * D_) + pair * (O_ * D_) + dg * 4;
#pragma unroll
    for (int o = 0; o < O_; ++o)
        *reinterpret_cast<float4*>(p + o * D_) = acc[o];
}

// ---------------------------------------------------------------------------
// Reduce partials -> s[b,o,d]; squash over d; update v_buf and output accum.
// mode 0: v_buf  = out ; d_out  = k*out      (iter 0)
// mode 1: v_buf += out ; d_out += k*out      (iter 1)
// mode 2:                d_out += k*out      (iter 2)
// pre: 0.1 folds the uniform softmax of iter 0; 1.0 otherwise.
// ---------------------------------------------------------------------------
__global__ __launch_bounds__(256)
void reduce_squash(const float* __restrict__ parts, float* __restrict__ v_buf,
                   float* __restrict__ out, float kscale, float pre, int mode)
{
    const int tid = threadIdx.x;
    const int g   = blockIdx.x * 16 + (tid >> 4);   // (b*O + o), 0..1279
    const int d   = tid & 15;
    const int idx = g * D_ + d;

    float s = 0.f;
    for (int p = 0; p < NBLK; ++p)
        s += parts[(long)p * (B_ * O_ * D_) + idx];
    s *= pre;

    float n2 = s * s;
    n2 += __shfl_xor(n2, 1);
    n2 += __shfl_xor(n2, 2);
    n2 += __shfl_xor(n2, 4);
    n2 += __shfl_xor(n2, 8);
    const float n     = sqrtf(n2);
    const float scale = n2 / ((1.f + n2) * (n + 1e-8f));
    const float o_    = scale * s;

    if (mode == 0)      { v_buf[idx] = o_;  out[idx]  = kscale * o_; }
    else if (mode == 1) { v_buf[idx] += o_; out[idx] += kscale * o_; }
    else                {                   out[idx] += kscale * o_; }
}

// ---------------------------------------------------------------------------
extern "C" void kernel_launch(void* const* d_in, const int* in_sizes, int n_in,
                              void* d_out, int out_size, void* d_ws, size_t ws_size,
                              hipStream_t stream)
{
    const float* x = (const float*)d_in[0];   // [128,4608,8]
    const float* w = (const float*)d_in[1];   // [10,4608,16,8]
    float* out   = (float*)d_out;             // [128,10,16]
    float* parts = (float*)d_ws;              // NBLK * 20480 floats = 21 MB
    float* v_buf = parts + (long)NBLK * (B_ * O_ * D_);

    // iter 0: c = 1/10 uniform
    pass_kernel<0><<<NBLK, 512, 0, stream>>>(x, w, nullptr, parts);
    reduce_squash<<<80, 256, 0, stream>>>(parts, v_buf, out, 0.3f, 0.1f, 0);

    // iter 1: b1 = <out0, xh>
    pass_kernel<1><<<NBLK, 512, 0, stream>>>(x, w, v_buf, parts);
    reduce_squash<<<80, 256, 0, stream>>>(parts, v_buf, out, 0.3f, 1.0f, 1);

    // iter 2: b2 = <out0 + out1, xh>
    pass_kernel<1><<<NBLK, 512, 0, stream>>>(x, w, v_buf, parts);
    reduce_squash<<<80, 256, 0, stream>>>(parts, v_buf, out, 0.4f, 1.0f, 2);
}